// Round 2
// baseline (365.643 us; speedup 1.0000x reference)
//
#include <hip/hip_runtime.h>

// feat: [N=8, C=2048, H=64, W=64] fp32
// proto: [K=21, C=2048] fp32
// out:  [N=8, K=21, H=64, W=64] fp32 = relu(cosine_sim over C)
//
// Memory-bound: 256 MiB feat read-once -> ~43 us floor @ 6.3 TB/s.
// Block = 1024 threads = 16 waves, grid = 256 = 1 block/CU.
// All 16 waves of a block cover the SAME 128 pixels (64 lanes x float2);
// wave w owns C-slice [w*128, w*128+128). Proto reads are wave-uniform
// (SGPR-indexed) -> scalar loads, L2-resident. Cross-wave reduction via
// 128 KB LDS in two chunks; each wave finalizes one k (parallel tail).

#define CDIM 2048
#define HW   4096
#define KNUM 21
#define EPS  1e-8f

__global__ __launch_bounds__(1024, 4)
void feat_proto_cos_kernel(const float* __restrict__ feat,
                           const float* __restrict__ proto,
                           float* __restrict__ out) {
    const int tid  = threadIdx.x;
    const int lane = tid & 63;
    // force wave id into SGPR so proto indexing is provably wave-uniform
    const int wv   = __builtin_amdgcn_readfirstlane(tid >> 6);   // 0..15
    const int b    = blockIdx.x;          // 0..255
    const int n    = b >> 5;              // image index
    const int hwb  = (b & 31) << 7;       // base pixel in HW plane
    const int px   = hwb + lane * 2;      // this lane's pixel pair

    __shared__ float  pnorm[KNUM];
    __shared__ float2 fnorm[64];          // feat norms for the 128 pixels
    __shared__ float2 red[16][1024];      // 128 KB reduction buffer

    // ---- prototype norms (redundant per block; proto is L2-resident) ----
    for (int k = wv; k < KNUM; k += 16) {
        float s = 0.f;
        for (int i = lane; i < CDIM; i += 64) {
            float p = proto[k * CDIM + i];
            s += p * p;
        }
        #pragma unroll
        for (int off = 32; off > 0; off >>= 1) s += __shfl_down(s, off);
        if (lane == 0) pnorm[k] = sqrtf(s);
    }

    // ---- main streaming loop: wave wv covers c in [wv*128, wv*128+128) ----
    const int c0 = wv * 128;
    const float* fp = feat + ((size_t)n * CDIM + c0) * HW + px;
    const float* pp = proto + c0;          // pp[k*CDIM + c] wave-uniform

    float2 acc[KNUM];
    #pragma unroll
    for (int k = 0; k < KNUM; ++k) acc[k] = make_float2(0.f, 0.f);
    float2 nrm = make_float2(0.f, 0.f);

    #pragma unroll 4
    for (int c = 0; c < 128; ++c) {
        float2 f = *(const float2*)(fp + (size_t)c * HW);
        nrm.x += f.x * f.x;
        nrm.y += f.y * f.y;
        #pragma unroll
        for (int k = 0; k < KNUM; ++k) {
            float p = pp[k * CDIM + c];    // wave-uniform -> s_load
            acc[k].x += f.x * p;
            acc[k].y += f.y * p;
        }
    }

    // ---- feat-norm cross-wave reduction ----
    red[0][tid] = nrm;
    __syncthreads();
    if (wv == 0) {
        float2 s = red[0][lane];
        #pragma unroll
        for (int w = 1; w < 16; ++w) {
            float2 t = red[0][w * 64 + lane];
            s.x += t.x; s.y += t.y;
        }
        fnorm[lane] = make_float2(sqrtf(s.x), sqrtf(s.y));
    }
    __syncthreads();
    const float2 fn = fnorm[lane];

    // ---- dot-product reduction, chunk 1: k = 0..15, one k per wave ----
    #pragma unroll   // full unroll: acc[] must stay register-indexed (rule #20)
    for (int kk = 0; kk < 16; ++kk) red[kk][tid] = acc[kk];
    __syncthreads();
    {
        const int k = wv;                  // 0..15
        float2 s = red[k][lane];
        #pragma unroll
        for (int w = 1; w < 16; ++w) {
            float2 t = red[k][w * 64 + lane];
            s.x += t.x; s.y += t.y;
        }
        const float pn = pnorm[k];
        float ox = fmaxf(s.x / fmaxf(fn.x * pn, EPS), 0.f);
        float oy = fmaxf(s.y / fmaxf(fn.y * pn, EPS), 0.f);
        *(float2*)(out + ((size_t)n * KNUM + k) * HW + px) = make_float2(ox, oy);
    }
    __syncthreads();

    // ---- chunk 2: k = 16..20, waves 0..4 ----
    #pragma unroll
    for (int kk = 0; kk < 5; ++kk) red[kk][tid] = acc[16 + kk];
    __syncthreads();
    if (wv < 5) {
        const int k = 16 + wv;
        float2 s = red[wv][lane];
        #pragma unroll
        for (int w = 1; w < 16; ++w) {
            float2 t = red[wv][w * 64 + lane];
            s.x += t.x; s.y += t.y;
        }
        const float pn = pnorm[k];
        float ox = fmaxf(s.x / fmaxf(fn.x * pn, EPS), 0.f);
        float oy = fmaxf(s.y / fmaxf(fn.y * pn, EPS), 0.f);
        *(float2*)(out + ((size_t)n * KNUM + k) * HW + px) = make_float2(ox, oy);
    }
}

extern "C" void kernel_launch(void* const* d_in, const int* in_sizes, int n_in,
                              void* d_out, int out_size, void* d_ws, size_t ws_size,
                              hipStream_t stream) {
    const float* feat  = (const float*)d_in[0];
    const float* proto = (const float*)d_in[1];
    // d_in[2] = class_numbers (fixed 21, baked into KNUM)
    float* out = (float*)d_out;

    feat_proto_cos_kernel<<<256, 1024, 0, stream>>>(feat, proto, out);
}